// Round 1
// baseline (813.847 us; speedup 1.0000x reference)
//
#include <hip/hip_runtime.h>
#include <hip/hip_bf16.h>

// GCN 2-layer forward on MI355X.
// dims fixed by problem: F=512, H=16, C=32. n, E derived from in_sizes.

__global__ __launch_bounds__(256) void k_init_deg(float* __restrict__ deg, int n) {
    int i = blockIdx.x * 256 + threadIdx.x;
    if (i < n) deg[i] = 1.0f;  // self-loop
}

__global__ __launch_bounds__(256) void k_count_deg(const int* __restrict__ dst,
                                                   float* __restrict__ deg, int E) {
    int e = blockIdx.x * 256 + threadIdx.x;
    if (e < E) unsafeAtomicAdd(&deg[dst[e]], 1.0f);
}

__global__ __launch_bounds__(256) void k_rsqrt_deg(float* __restrict__ deg, int n) {
    int i = blockIdx.x * 256 + threadIdx.x;
    if (i < n) deg[i] = rsqrtf(deg[i]);  // deg >= 1 always
}

// h1 = x @ W1  [n,512]@[512,16]; also r1[i][k] = h1[i][k]*dinv[i]^2 (self-loop init).
// Wave-per-row: lane = (g<<4)|q ; q=output col k, g=quarter of the 512-dim j range.
// W1 staged in LDS at idx ((j&127)*4 + (j>>7))*17 + q  -> groups land 17 banks apart
// (mostly 2-way conflicts, which are free on CDNA4).
__global__ __launch_bounds__(256) void k_gemm1(const float* __restrict__ x,
                                               const float* __restrict__ W1,
                                               const float* __restrict__ dinv,
                                               float* __restrict__ h1,
                                               float* __restrict__ r1, int n) {
    __shared__ float Ws[512 * 17 + 16];
    for (int t = threadIdx.x; t < 512 * 16; t += 256) {
        int j = t >> 4, q = t & 15;
        int idx = ((j & 127) << 2) | (j >> 7);
        Ws[idx * 17 + q] = W1[t];
    }
    __syncthreads();
    const int wave = threadIdx.x >> 6;
    const int lane = threadIdx.x & 63;
    const int q = lane & 15, g = lane >> 4;
    const int nwaves = gridDim.x * 4;
    for (int row = blockIdx.x * 4 + wave; row < n; row += nwaves) {
        const float4* xr = reinterpret_cast<const float4*>(x + (size_t)row * 512 + g * 128);
        float acc = 0.f;
#pragma unroll 8
        for (int t = 0; t < 32; ++t) {
            float4 xv = xr[t];
            int r0 = t * 4;
            acc += xv.x * Ws[(((r0 + 0) << 2) | g) * 17 + q];
            acc += xv.y * Ws[(((r0 + 1) << 2) | g) * 17 + q];
            acc += xv.z * Ws[(((r0 + 2) << 2) | g) * 17 + q];
            acc += xv.w * Ws[(((r0 + 3) << 2) | g) * 17 + q];
        }
        acc += __shfl_xor(acc, 16);
        acc += __shfl_xor(acc, 32);
        if (lane < 16) {
            float dv = dinv[row];
            h1[(size_t)row * 16 + q] = acc;
            r1[(size_t)row * 16 + q] = acc * dv * dv;
        }
    }
}

// r1[dst][k] += h1[src][k] * dinv[src]*dinv[dst], 16 lanes per edge.
__global__ __launch_bounds__(256) void k_scatter1(const int* __restrict__ src,
                                                  const int* __restrict__ dst,
                                                  const float* __restrict__ h1,
                                                  const float* __restrict__ dinv,
                                                  float* __restrict__ r1, int total) {
    int t = blockIdx.x * 256 + threadIdx.x;
    if (t >= total) return;
    int e = t >> 4, k = t & 15;
    int s = src[e], d = dst[e];
    float w = dinv[s] * dinv[d];
    unsafeAtomicAdd(&r1[(size_t)d * 16 + k], h1[(size_t)s * 16 + k] * w);
}

// h2 = relu(r1 + b1) @ W2  [n,16]@[16,32]; one thread per (i,c).
__global__ __launch_bounds__(256) void k_layer2(const float* __restrict__ r1,
                                                const float* __restrict__ W2,
                                                const float* __restrict__ b1,
                                                float* __restrict__ h2, int n) {
    __shared__ float Ws[16 * 33];
    __shared__ float bs[16];
    for (int t = threadIdx.x; t < 512; t += 256) Ws[(t >> 5) * 33 + (t & 31)] = W2[t];
    if (threadIdx.x < 16) bs[threadIdx.x] = b1[threadIdx.x];
    __syncthreads();
    int t = blockIdx.x * 256 + threadIdx.x;
    int i = t >> 5, c = t & 31;
    if (i >= n) return;
    const float4* rr = reinterpret_cast<const float4*>(r1 + (size_t)i * 16);
    float acc = 0.f;
#pragma unroll
    for (int kk = 0; kk < 4; ++kk) {
        float4 v = rr[kk];
        acc += fmaxf(v.x + bs[4 * kk + 0], 0.f) * Ws[(4 * kk + 0) * 33 + c];
        acc += fmaxf(v.y + bs[4 * kk + 1], 0.f) * Ws[(4 * kk + 1) * 33 + c];
        acc += fmaxf(v.z + bs[4 * kk + 2], 0.f) * Ws[(4 * kk + 2) * 33 + c];
        acc += fmaxf(v.w + bs[4 * kk + 3], 0.f) * Ws[(4 * kk + 3) * 33 + c];
    }
    h2[t] = acc;
}

// agg2[i][c] = h2[i][c]*dinv[i]^2 (self-loop init)
__global__ __launch_bounds__(256) void k_init_agg2(const float* __restrict__ h2,
                                                   const float* __restrict__ dinv,
                                                   float* __restrict__ agg2, int total) {
    int t = blockIdx.x * 256 + threadIdx.x;
    if (t >= total) return;
    int i = t >> 5;
    float dv = dinv[i];
    agg2[t] = h2[t] * dv * dv;
}

// agg2[dst][c] += h2[src][c] * dinv[src]*dinv[dst], 32 lanes per edge.
__global__ __launch_bounds__(256) void k_scatter2(const int* __restrict__ src,
                                                  const int* __restrict__ dst,
                                                  const float* __restrict__ h2,
                                                  const float* __restrict__ dinv,
                                                  float* __restrict__ agg2, int total) {
    int t = blockIdx.x * 256 + threadIdx.x;
    if (t >= total) return;
    int e = t >> 5, c = t & 31;
    int s = src[e], d = dst[e];
    float w = dinv[s] * dinv[d];
    unsafeAtomicAdd(&agg2[(size_t)d * 32 + c], h2[(size_t)s * 32 + c] * w);
}

// out = log_softmax(agg2 + b2) over rows of 32; width-32 shuffle reductions.
__global__ __launch_bounds__(256) void k_lsm(const float* __restrict__ agg2,
                                             const float* __restrict__ b2,
                                             float* __restrict__ out, int total) {
    int t = blockIdx.x * 256 + threadIdx.x;
    if (t >= total) return;
    int c = t & 31;
    float v = agg2[t] + b2[c];
    float m = v;
#pragma unroll
    for (int o = 16; o > 0; o >>= 1) m = fmaxf(m, __shfl_xor(m, o, 32));
    float p = expf(v - m);
#pragma unroll
    for (int o = 16; o > 0; o >>= 1) p += __shfl_xor(p, o, 32);
    out[t] = v - m - logf(p);
}

extern "C" void kernel_launch(void* const* d_in, const int* in_sizes, int n_in,
                              void* d_out, int out_size, void* d_ws, size_t ws_size,
                              hipStream_t stream) {
    const float* x  = (const float*)d_in[0];
    const int* ei   = (const int*)d_in[1];
    const float* W1 = (const float*)d_in[2];
    const float* b1 = (const float*)d_in[3];
    const float* W2 = (const float*)d_in[4];
    const float* b2 = (const float*)d_in[5];
    float* out = (float*)d_out;

    const int n = in_sizes[0] / 512;   // 100000
    const int E = in_sizes[1] / 2;     // 3200000
    const int* src = ei;
    const int* dst = ei + E;

    // ws layout (floats): dinv[n] | h1[16n] | r1[16n]; agg2[32n] reuses h1|r1 region.
    float* ws   = (float*)d_ws;
    float* dinv = ws;
    float* h1   = ws + n;
    float* r1   = ws + n + 16 * (size_t)n;
    float* agg2 = ws + n;

    const int total1 = E * 16;   // 51.2M
    const int total2 = E * 32;   // 102.4M
    const int totn2  = n * 32;   // 3.2M

    k_init_deg <<<(n + 255) / 256, 256, 0, stream>>>(dinv, n);
    k_count_deg<<<(E + 255) / 256, 256, 0, stream>>>(dst, dinv, E);
    k_rsqrt_deg<<<(n + 255) / 256, 256, 0, stream>>>(dinv, n);
    k_gemm1    <<<1024, 256, 0, stream>>>(x, W1, dinv, h1, r1, n);
    k_scatter1 <<<(total1 + 255) / 256, 256, 0, stream>>>(src, dst, h1, dinv, r1, total1);
    k_layer2   <<<(totn2 + 255) / 256, 256, 0, stream>>>(r1, W2, b1, out, n);
    k_init_agg2<<<(totn2 + 255) / 256, 256, 0, stream>>>(out, dinv, agg2, totn2);
    k_scatter2 <<<(total2 + 255) / 256, 256, 0, stream>>>(src, dst, out, dinv, agg2, total2);
    k_lsm      <<<(totn2 + 255) / 256, 256, 0, stream>>>(agg2, b2, out, totn2);
}

// Round 2
// 537.375 us; speedup vs baseline: 1.5145x; 1.5145x over previous
//
#include <hip/hip_runtime.h>
#include <hip/hip_bf16.h>

// GCN 2-layer forward, MI355X. F=512, H=16, C=32.
// Strategy: CSR-bin edges by dst once (no feature atomics), aggregate by gather.
// Layer2 uses associativity: A(R W2)+b2 = (A R) W2 + b2 -> aggregate at width 16.

__global__ __launch_bounds__(256) void k_zero_i(int* __restrict__ p, int n) {
    int i = blockIdx.x * 256 + threadIdx.x;
    if (i < n) p[i] = 0;
}

__global__ __launch_bounds__(256) void k_count(const int* __restrict__ dst,
                                               int* __restrict__ cnt, int E) {
    int e = blockIdx.x * 256 + threadIdx.x;
    if (e < E) atomicAdd(&cnt[dst[e]], 1);
}

// dinv only (fallback path)
__global__ __launch_bounds__(256) void k_dinv(const int* __restrict__ cnt,
                                              float* __restrict__ dinv, int n) {
    int i = blockIdx.x * 256 + threadIdx.x;
    if (i < n) dinv[i] = rsqrtf((float)(cnt[i] + 1));
}

#define SCAN_B 1024
__global__ __launch_bounds__(1024) void k_scan1(const int* __restrict__ cnt,
                                                int* __restrict__ offs,
                                                int* __restrict__ bsum, int n) {
    __shared__ int sm[SCAN_B];
    int tid = threadIdx.x;
    int i = blockIdx.x * SCAN_B + tid;
    int c = (i < n) ? cnt[i] : 0;
    sm[tid] = c;
    __syncthreads();
    for (int o = 1; o < SCAN_B; o <<= 1) {
        int t = (tid >= o) ? sm[tid - o] : 0;
        __syncthreads();
        sm[tid] += t;
        __syncthreads();
    }
    if (i < n) offs[i] = sm[tid] - c;  // within-block exclusive
    if (tid == SCAN_B - 1) bsum[blockIdx.x] = sm[tid];
}

__global__ __launch_bounds__(1024) void k_scan2(int* __restrict__ bsum, int nb) {
    __shared__ int sm[SCAN_B];
    int tid = threadIdx.x;
    int c = (tid < nb) ? bsum[tid] : 0;
    sm[tid] = c;
    __syncthreads();
    for (int o = 1; o < SCAN_B; o <<= 1) {
        int t = (tid >= o) ? sm[tid - o] : 0;
        __syncthreads();
        sm[tid] += t;
        __syncthreads();
    }
    if (tid < nb) bsum[tid] = sm[tid] - c;  // exclusive block sums
}

__global__ __launch_bounds__(256) void k_scan3(int* __restrict__ offs,
                                               const int* __restrict__ bsum,
                                               int* __restrict__ cursor,
                                               const int* __restrict__ cnt,
                                               float* __restrict__ dinv, int n, int E) {
    int i = blockIdx.x * 256 + threadIdx.x;
    if (i < n) {
        int o = offs[i] + bsum[i >> 10];
        offs[i] = o;
        cursor[i] = o;
        dinv[i] = rsqrtf((float)(cnt[i] + 1));
    }
    if (i == 0) offs[n] = E;
}

__global__ __launch_bounds__(256) void k_fill(const int* __restrict__ src,
                                              const int* __restrict__ dst,
                                              const float* __restrict__ dinv,
                                              int* __restrict__ cursor,
                                              int2* __restrict__ bq, int E) {
    int e = blockIdx.x * 256 + threadIdx.x;
    if (e >= E) return;
    int s = src[e], d = dst[e];
    float w = dinv[s] * dinv[d];
    int p = atomicAdd(&cursor[d], 1);
    bq[p] = make_int2(s, __float_as_int(w));
}

// h1 = x @ W1; optionally r1self = h1*dinv^2 (fallback path only).
__global__ __launch_bounds__(256) void k_gemm1(const float* __restrict__ x,
                                               const float* __restrict__ W1,
                                               const float* __restrict__ dinv,
                                               float* __restrict__ h1,
                                               float* __restrict__ r1self, int n) {
    __shared__ float Ws[512 * 17 + 16];
    for (int t = threadIdx.x; t < 512 * 16; t += 256) {
        int j = t >> 4, q = t & 15;
        int idx = ((j & 127) << 2) | (j >> 7);
        Ws[idx * 17 + q] = W1[t];
    }
    __syncthreads();
    const int wave = threadIdx.x >> 6;
    const int lane = threadIdx.x & 63;
    const int q = lane & 15, g = lane >> 4;
    const int nwaves = gridDim.x * 4;
    for (int row = blockIdx.x * 4 + wave; row < n; row += nwaves) {
        const float4* xr = reinterpret_cast<const float4*>(x + (size_t)row * 512 + g * 128);
        float acc = 0.f;
#pragma unroll 8
        for (int t = 0; t < 32; ++t) {
            float4 xv = xr[t];
            int r0 = t * 4;
            acc += xv.x * Ws[(((r0 + 0) << 2) | g) * 17 + q];
            acc += xv.y * Ws[(((r0 + 1) << 2) | g) * 17 + q];
            acc += xv.z * Ws[(((r0 + 2) << 2) | g) * 17 + q];
            acc += xv.w * Ws[(((r0 + 3) << 2) | g) * 17 + q];
        }
        acc += __shfl_xor(acc, 16);
        acc += __shfl_xor(acc, 32);
        if (lane < 16) {
            h1[(size_t)row * 16 + q] = acc;
            if (r1self) {
                float dv = dinv[row];
                r1self[(size_t)row * 16 + q] = acc * dv * dv;
            }
        }
    }
}

// Gather aggregation: out[i][k] = feat[i][k]*dinv[i]^2 + sum_p w_p * feat[src_p][k]
// 16 lanes per node. relu_flag: out = relu(out + bias[k]).
__global__ __launch_bounds__(256) void k_agg(const float* __restrict__ feat,
                                             const int2* __restrict__ bq,
                                             const int* __restrict__ offs,
                                             const float* __restrict__ dinv,
                                             const float* __restrict__ bias,
                                             float* __restrict__ outf, int n, int relu_flag) {
    int t = blockIdx.x * 256 + threadIdx.x;
    int i = t >> 4, k = t & 15;
    if (i >= n) return;
    float dv = dinv[i];
    float acc = feat[(size_t)i * 16 + k] * dv * dv;
    int p = offs[i], p1 = offs[i + 1];
    for (; p + 4 <= p1; p += 4) {
        int2 q0 = bq[p], q1 = bq[p + 1], q2 = bq[p + 2], q3 = bq[p + 3];
        acc += __int_as_float(q0.y) * feat[(size_t)q0.x * 16 + k];
        acc += __int_as_float(q1.y) * feat[(size_t)q1.x * 16 + k];
        acc += __int_as_float(q2.y) * feat[(size_t)q2.x * 16 + k];
        acc += __int_as_float(q3.y) * feat[(size_t)q3.x * 16 + k];
    }
    for (; p < p1; ++p) {
        int2 q = bq[p];
        acc += __int_as_float(q.y) * feat[(size_t)q.x * 16 + k];
    }
    if (relu_flag) acc = fmaxf(acc + bias[k], 0.f);
    outf[(size_t)i * 16 + k] = acc;
}

// Fallback path kernels (atomic scatter, width 16)
__global__ __launch_bounds__(256) void k_scatter16(const int* __restrict__ src,
                                                   const int* __restrict__ dst,
                                                   const float* __restrict__ feat,
                                                   const float* __restrict__ dinv,
                                                   float* __restrict__ outf, int total) {
    int t = blockIdx.x * 256 + threadIdx.x;
    if (t >= total) return;
    int e = t >> 4, k = t & 15;
    int s = src[e], d = dst[e];
    float w = dinv[s] * dinv[d];
    unsafeAtomicAdd(&outf[(size_t)d * 16 + k], feat[(size_t)s * 16 + k] * w);
}

__global__ __launch_bounds__(256) void k_relu16(float* __restrict__ r1,
                                                const float* __restrict__ b1, int total) {
    int t = blockIdx.x * 256 + threadIdx.x;
    if (t < total) r1[t] = fmaxf(r1[t] + b1[t & 15], 0.f);
}

__global__ __launch_bounds__(256) void k_self16(const float* __restrict__ feat,
                                                const float* __restrict__ dinv,
                                                float* __restrict__ outf, int total) {
    int t = blockIdx.x * 256 + threadIdx.x;
    if (t >= total) return;
    float dv = dinv[t >> 4];
    outf[t] = feat[t] * dv * dv;
}

// out = log_softmax(a @ W2 + b2), a is [n,16], out [n,32]. 32 lanes/node.
__global__ __launch_bounds__(256) void k_out(const float* __restrict__ a,
                                             const float* __restrict__ W2,
                                             const float* __restrict__ b2,
                                             float* __restrict__ out, int n) {
    __shared__ float Ws[16 * 33];
    __shared__ float bs[32];
    for (int t = threadIdx.x; t < 512; t += 256) Ws[(t >> 5) * 33 + (t & 31)] = W2[t];
    if (threadIdx.x < 32) bs[threadIdx.x] = b2[threadIdx.x];
    __syncthreads();
    int t = blockIdx.x * 256 + threadIdx.x;
    int i = t >> 5, c = t & 31;
    if (i >= n) return;
    const float4* ar = reinterpret_cast<const float4*>(a + (size_t)i * 16);
    float acc = bs[c];
#pragma unroll
    for (int kk = 0; kk < 4; ++kk) {
        float4 v = ar[kk];
        acc += v.x * Ws[(4 * kk + 0) * 33 + c];
        acc += v.y * Ws[(4 * kk + 1) * 33 + c];
        acc += v.z * Ws[(4 * kk + 2) * 33 + c];
        acc += v.w * Ws[(4 * kk + 3) * 33 + c];
    }
    float m = acc;
#pragma unroll
    for (int o = 16; o > 0; o >>= 1) m = fmaxf(m, __shfl_xor(m, o, 32));
    float p = expf(acc - m);
#pragma unroll
    for (int o = 16; o > 0; o >>= 1) p += __shfl_xor(p, o, 32);
    out[t] = acc - m - logf(p);
}

extern "C" void kernel_launch(void* const* d_in, const int* in_sizes, int n_in,
                              void* d_out, int out_size, void* d_ws, size_t ws_size,
                              hipStream_t stream) {
    const float* x  = (const float*)d_in[0];
    const int* ei   = (const int*)d_in[1];
    const float* W1 = (const float*)d_in[2];
    const float* b1 = (const float*)d_in[3];
    const float* W2 = (const float*)d_in[4];
    const float* b2 = (const float*)d_in[5];
    float* out = (float*)d_out;

    const int n = in_sizes[0] / 512;
    const int E = in_sizes[1] / 2;
    const int* src = ei;
    const int* dst = ei + E;

    float* ws = (float*)d_ws;
    const int nb = (n + SCAN_B - 1) / SCAN_B;

    // Bucket-path layout (4B units):
    // dinv[n] | offs[n+16] | cursor[n] | bsum[1024] | bq[2E] | h1[16n] | r1[16n]
    // cnt aliases h1 (dead after scan3, before gemm1 writes h1). agg2r aliases h1.
    size_t u_dinv = 0;
    size_t u_offs = u_dinv + n;
    size_t u_cur  = u_offs + n + 16;
    size_t u_bsum = u_cur + n;
    size_t u_bq   = u_bsum + 1024;
    size_t u_h1   = u_bq + 2 * (size_t)E;
    size_t u_r1   = u_h1 + 16 * (size_t)n;
    size_t need   = (u_r1 + 16 * (size_t)n) * 4;

    if (ws_size >= need) {
        float* dinv = ws + u_dinv;
        int* offs   = (int*)(ws + u_offs);
        int* cursor = (int*)(ws + u_cur);
        int* bsum   = (int*)(ws + u_bsum);
        int2* bq    = (int2*)(ws + u_bq);
        float* h1   = ws + u_h1;
        float* r1   = ws + u_r1;
        int* cnt    = (int*)h1;      // alias
        float* agg2r = h1;           // alias (h1 dead after first k_agg)

        k_zero_i<<<(n + 255) / 256, 256, 0, stream>>>(cnt, n);
        k_count <<<(E + 255) / 256, 256, 0, stream>>>(dst, cnt, E);
        k_scan1 <<<nb, SCAN_B, 0, stream>>>(cnt, offs, bsum, n);
        k_scan2 <<<1, SCAN_B, 0, stream>>>(bsum, nb);
        k_scan3 <<<(n + 255) / 256, 256, 0, stream>>>(offs, bsum, cursor, cnt, dinv, n, E);
        k_gemm1 <<<1024, 256, 0, stream>>>(x, W1, dinv, h1, nullptr, n);
        k_fill  <<<(E + 255) / 256, 256, 0, stream>>>(src, dst, dinv, cursor, bq, E);
        k_agg   <<<(n * 16 + 255) / 256, 256, 0, stream>>>(h1, bq, offs, dinv, b1, r1, n, 1);
        k_agg   <<<(n * 16 + 255) / 256, 256, 0, stream>>>(r1, bq, offs, dinv, b1, agg2r, n, 0);
        k_out   <<<(n * 32 + 255) / 256, 256, 0, stream>>>(agg2r, W2, b2, out, n);
    } else {
        // Fallback: atomic scatters (both width 16). Layout: dinv[n] | h1[16n] | r1[16n]
        float* dinv = ws;
        float* h1   = ws + n;
        float* r1   = ws + n + 16 * (size_t)n;
        int* cnt    = (int*)h1;   // alias, dead before gemm1
        float* agg2r = h1;        // alias, h1 dead after scatter1

        const int total1 = E * 16;
        k_zero_i   <<<(n + 255) / 256, 256, 0, stream>>>(cnt, n);
        k_count    <<<(E + 255) / 256, 256, 0, stream>>>(dst, cnt, E);
        k_dinv     <<<(n + 255) / 256, 256, 0, stream>>>(cnt, dinv, n);
        k_gemm1    <<<1024, 256, 0, stream>>>(x, W1, dinv, h1, r1, n);
        k_scatter16<<<(total1 + 255) / 256, 256, 0, stream>>>(src, dst, h1, dinv, r1, total1);
        k_relu16   <<<(n * 16 + 255) / 256, 256, 0, stream>>>(r1, b1, n * 16);
        k_self16   <<<(n * 16 + 255) / 256, 256, 0, stream>>>(r1, dinv, agg2r, n * 16);
        k_scatter16<<<(total1 + 255) / 256, 256, 0, stream>>>(src, dst, r1, dinv, agg2r, total1);
        k_out      <<<(n * 32 + 255) / 256, 256, 0, stream>>>(agg2r, W2, b2, out, n);
    }
}

// Round 3
// 492.925 us; speedup vs baseline: 1.6511x; 1.0902x over previous
//
#include <hip/hip_runtime.h>
#include <hip/hip_bf16.h>

// GCN 2-layer forward, MI355X. F=512, H=16, C=32.
// CSR-bin edges by dst (no feature atomics), gather aggregation.
// Layer2 associativity: A(R W2)+b2 = (A R) W2 + b2 -> aggregate at width 16.
// gemm1: 8 rows/wave, async global_load_lds double-buffered x staging,
// barrier-free per-wave vmcnt pipeline, swizzled W in LDS.

__device__ __forceinline__ void load_lds16(const float* g, void* l) {
    __builtin_amdgcn_global_load_lds((const __attribute__((address_space(1))) void*)g,
                                     (__attribute__((address_space(3))) void*)l, 16, 0, 0);
}

__global__ __launch_bounds__(256) void k_zero_i(int* __restrict__ p, int n) {
    int i = blockIdx.x * 256 + threadIdx.x;
    if (i < n) p[i] = 0;
}

__global__ __launch_bounds__(256) void k_count(const int* __restrict__ dst,
                                               int* __restrict__ cnt, int E) {
    int e = blockIdx.x * 256 + threadIdx.x;
    if (e < E) atomicAdd(&cnt[dst[e]], 1);
}

__global__ __launch_bounds__(256) void k_dinv(const int* __restrict__ cnt,
                                              float* __restrict__ dinv, int n) {
    int i = blockIdx.x * 256 + threadIdx.x;
    if (i < n) dinv[i] = rsqrtf((float)(cnt[i] + 1));
}

#define SCAN_B 1024
__global__ __launch_bounds__(1024) void k_scan1(const int* __restrict__ cnt,
                                                int* __restrict__ offs,
                                                int* __restrict__ bsum, int n) {
    __shared__ int sm[SCAN_B];
    int tid = threadIdx.x;
    int i = blockIdx.x * SCAN_B + tid;
    int c = (i < n) ? cnt[i] : 0;
    sm[tid] = c;
    __syncthreads();
    for (int o = 1; o < SCAN_B; o <<= 1) {
        int t = (tid >= o) ? sm[tid - o] : 0;
        __syncthreads();
        sm[tid] += t;
        __syncthreads();
    }
    if (i < n) offs[i] = sm[tid] - c;
    if (tid == SCAN_B - 1) bsum[blockIdx.x] = sm[tid];
}

__global__ __launch_bounds__(1024) void k_scan2(int* __restrict__ bsum, int nb) {
    __shared__ int sm[SCAN_B];
    int tid = threadIdx.x;
    int c = (tid < nb) ? bsum[tid] : 0;
    sm[tid] = c;
    __syncthreads();
    for (int o = 1; o < SCAN_B; o <<= 1) {
        int t = (tid >= o) ? sm[tid - o] : 0;
        __syncthreads();
        sm[tid] += t;
        __syncthreads();
    }
    if (tid < nb) bsum[tid] = sm[tid] - c;
}

__global__ __launch_bounds__(256) void k_scan3(int* __restrict__ offs,
                                               const int* __restrict__ bsum,
                                               int* __restrict__ cursor,
                                               const int* __restrict__ cnt,
                                               float* __restrict__ dinv, int n, int E) {
    int i = blockIdx.x * 256 + threadIdx.x;
    if (i < n) {
        int o = offs[i] + bsum[i >> 10];
        offs[i] = o;
        cursor[i] = o;
        dinv[i] = rsqrtf((float)(cnt[i] + 1));
    }
    if (i == 0) offs[n] = E;
}

__global__ __launch_bounds__(256) void k_fill(const int* __restrict__ src,
                                              const int* __restrict__ dst,
                                              const float* __restrict__ dinv,
                                              int* __restrict__ cursor,
                                              int2* __restrict__ bq, int E) {
    int e = blockIdx.x * 256 + threadIdx.x;
    if (e >= E) return;
    int s = src[e], d = dst[e];
    float w = dinv[s] * dinv[d];
    int p = atomicAdd(&cursor[d], 1);
    bq[p] = make_int2(s, __float_as_int(w));
}

// h1 = x @ W1 [n,512]@[512,16]. 8 rows per wave. Async LDS staging of x,
// per-wave 2-deep chunk pipeline (chunk = [8 rows][128 floats] = 4KB).
// Lane = (g in 0..3, q in 0..15): q = out col, g = j-subchunk.
// W in LDS with XOR-bit4 swizzle (a ^= ((a>>9)&1)<<4) -> <=2-way conflicts.
// x reads rotated by g (tg=(t+g)&7) -> conflict-free ds_read_b128.
__global__ __launch_bounds__(256) void k_gemm1(const float* __restrict__ x,
                                               const float* __restrict__ W1,
                                               const float* __restrict__ dinv,
                                               float* __restrict__ h1,
                                               float* __restrict__ r1self, int n) {
    __shared__ float Ws[8192];        // 32KB swizzled W
    __shared__ float4 Xs[4][512];     // 32KB: per-wave 2 x 256 float4 ring
    for (int t = threadIdx.x; t < 8192; t += 256) {
        int sa = t ^ (((t >> 9) & 1) << 4);
        Ws[sa] = W1[t];
    }
    __syncthreads();

    const int wave = threadIdx.x >> 6;
    const int lane = threadIdx.x & 63;
    const int q = lane & 15, g = lane >> 4;
    const int sr = lane >> 3, su = lane & 7;   // staging: row, float4-slot
    const int first = blockIdx.x * 4 + wave;
    const int stride = gridDim.x * 4;
    const int ngroups = (n + 7) >> 3;
    if (first >= ngroups) return;
    const int mygroups = (ngroups - first + stride - 1) / stride;
    const int T = mygroups * 4;  // chunks (4 per group)

    char* xbase = (char*)(&Xs[wave][0]);

    // stage chunk i: group k=i>>2, j-chunk c=i&3, buffer i&1
    auto stage = [&](int i) {
        int k = i >> 2, c = i & 3;
        int r0 = (first + k * stride) << 3;
        int row = r0 + sr;
        if (row >= n) row = n - 1;
        const float* gp = x + (size_t)row * 512 + c * 128 + su * 4;
        char* lb = xbase + (i & 1) * 4096;
#pragma unroll
        for (int m = 0; m < 4; ++m)
            load_lds16(gp + m * 32, lb + m * 1024);
    };

    stage(0);
    if (T > 1) stage(1);
    int issued = (T > 1) ? 2 : 1;

    float acc[8];
    const float4* xw = &Xs[wave][0];
    const int flip = (g & 1) << 4;

    for (int i = 0; i < T; ++i) {
        if (i < T - 1) {
            asm volatile("s_waitcnt vmcnt(4)" ::: "memory");
        } else {
            asm volatile("s_waitcnt vmcnt(0)" ::: "memory");
        }
        int c = i & 3;
        const float4* xb = xw + (i & 1) * 256;
        if (c == 0) {
#pragma unroll
            for (int r = 0; r < 8; ++r) acc[r] = 0.f;
        }
        const int aW = 2048 * c + 512 * g + q;
#pragma unroll
        for (int t = 0; t < 8; ++t) {
            int tg = (t + g) & 7;
            float4 xv[8];
#pragma unroll
            for (int r = 0; r < 8; ++r) xv[r] = xb[g * 64 + r * 8 + tg];
            int a0 = aW + 64 * tg;
            float w0 = Ws[(a0) ^ flip];
            float w1 = Ws[(a0 + 16) ^ flip];
            float w2 = Ws[(a0 + 32) ^ flip];
            float w3 = Ws[(a0 + 48) ^ flip];
#pragma unroll
            for (int r = 0; r < 8; ++r)
                acc[r] += xv[r].x * w0 + xv[r].y * w1 + xv[r].z * w2 + xv[r].w * w3;
        }
        if (issued < T) { stage(issued); ++issued; }
        if (c == 3) {
            int r0 = (first + (i >> 2) * stride) << 3;
#pragma unroll
            for (int r = 0; r < 8; ++r) {
                acc[r] += __shfl_xor(acc[r], 16);
                acc[r] += __shfl_xor(acc[r], 32);
            }
            // static-index select of acc[g], acc[g+4] (avoid scratch)
            float v0 = 0.f, v1 = 0.f;
#pragma unroll
            for (int r = 0; r < 4; ++r) {
                if (g == r) { v0 = acc[r]; v1 = acc[r + 4]; }
            }
            int row0 = r0 + g, row1 = r0 + 4 + g;
            if (row0 < n) {
                h1[(size_t)row0 * 16 + q] = v0;
                if (r1self) {
                    float dv = dinv[row0];
                    r1self[(size_t)row0 * 16 + q] = v0 * dv * dv;
                }
            }
            if (row1 < n) {
                h1[(size_t)row1 * 16 + q] = v1;
                if (r1self) {
                    float dv = dinv[row1];
                    r1self[(size_t)row1 * 16 + q] = v1 * dv * dv;
                }
            }
        }
    }
}

// Gather aggregation: out[i][k] = feat[i][k]*dinv[i]^2 + sum_p w_p*feat[src_p][k]
__global__ __launch_bounds__(256) void k_agg(const float* __restrict__ feat,
                                             const int2* __restrict__ bq,
                                             const int* __restrict__ offs,
                                             const float* __restrict__ dinv,
                                             const float* __restrict__ bias,
                                             float* __restrict__ outf, int n, int relu_flag) {
    int t = blockIdx.x * 256 + threadIdx.x;
    int i = t >> 4, k = t & 15;
    if (i >= n) return;
    float dv = dinv[i];
    float acc = feat[(size_t)i * 16 + k] * dv * dv;
    int p = offs[i], p1 = offs[i + 1];
    for (; p + 4 <= p1; p += 4) {
        int2 q0 = bq[p], q1 = bq[p + 1], q2 = bq[p + 2], q3 = bq[p + 3];
        acc += __int_as_float(q0.y) * feat[(size_t)q0.x * 16 + k];
        acc += __int_as_float(q1.y) * feat[(size_t)q1.x * 16 + k];
        acc += __int_as_float(q2.y) * feat[(size_t)q2.x * 16 + k];
        acc += __int_as_float(q3.y) * feat[(size_t)q3.x * 16 + k];
    }
    for (; p < p1; ++p) {
        int2 q = bq[p];
        acc += __int_as_float(q.y) * feat[(size_t)q.x * 16 + k];
    }
    if (relu_flag) acc = fmaxf(acc + bias[k], 0.f);
    outf[(size_t)i * 16 + k] = acc;
}

// Fallback path kernels (atomic scatter, width 16)
__global__ __launch_bounds__(256) void k_scatter16(const int* __restrict__ src,
                                                   const int* __restrict__ dst,
                                                   const float* __restrict__ feat,
                                                   const float* __restrict__ dinv,
                                                   float* __restrict__ outf, int total) {
    int t = blockIdx.x * 256 + threadIdx.x;
    if (t >= total) return;
    int e = t >> 4, k = t & 15;
    int s = src[e], d = dst[e];
    float w = dinv[s] * dinv[d];
    unsafeAtomicAdd(&outf[(size_t)d * 16 + k], feat[(size_t)s * 16 + k] * w);
}

__global__ __launch_bounds__(256) void k_relu16(float* __restrict__ r1,
                                                const float* __restrict__ b1, int total) {
    int t = blockIdx.x * 256 + threadIdx.x;
    if (t < total) r1[t] = fmaxf(r1[t] + b1[t & 15], 0.f);
}

__global__ __launch_bounds__(256) void k_self16(const float* __restrict__ feat,
                                                const float* __restrict__ dinv,
                                                float* __restrict__ outf, int total) {
    int t = blockIdx.x * 256 + threadIdx.x;
    if (t >= total) return;
    float dv = dinv[t >> 4];
    outf[t] = feat[t] * dv * dv;
}

// out = log_softmax(a @ W2 + b2), a [n,16] -> out [n,32]. 32 lanes/node.
__global__ __launch_bounds__(256) void k_out(const float* __restrict__ a,
                                             const float* __restrict__ W2,
                                             const float* __restrict__ b2,
                                             float* __restrict__ out, int n) {
    __shared__ float Ws[16 * 33];
    __shared__ float bs[32];
    for (int t = threadIdx.x; t < 512; t += 256) Ws[(t >> 5) * 33 + (t & 31)] = W2[t];
    if (threadIdx.x < 32) bs[threadIdx.x] = b2[threadIdx.x];
    __syncthreads();
    int t = blockIdx.x * 256 + threadIdx.x;
    int i = t >> 5, c = t & 31;
    if (i >= n) return;
    const float4* ar = reinterpret_cast<const float4*>(a + (size_t)i * 16);
    float acc = bs[c];
#pragma unroll
    for (int kk = 0; kk < 4; ++kk) {
        float4 v = ar[kk];
        acc += v.x * Ws[(4 * kk + 0) * 33 + c];
        acc += v.y * Ws[(4 * kk + 1) * 33 + c];
        acc += v.z * Ws[(4 * kk + 2) * 33 + c];
        acc += v.w * Ws[(4 * kk + 3) * 33 + c];
    }
    float m = acc;
#pragma unroll
    for (int o = 16; o > 0; o >>= 1) m = fmaxf(m, __shfl_xor(m, o, 32));
    float p = expf(acc - m);
#pragma unroll
    for (int o = 16; o > 0; o >>= 1) p += __shfl_xor(p, o, 32);
    out[t] = acc - m - logf(p);
}

extern "C" void kernel_launch(void* const* d_in, const int* in_sizes, int n_in,
                              void* d_out, int out_size, void* d_ws, size_t ws_size,
                              hipStream_t stream) {
    const float* x  = (const float*)d_in[0];
    const int* ei   = (const int*)d_in[1];
    const float* W1 = (const float*)d_in[2];
    const float* b1 = (const float*)d_in[3];
    const float* W2 = (const float*)d_in[4];
    const float* b2 = (const float*)d_in[5];
    float* out = (float*)d_out;

    const int n = in_sizes[0] / 512;
    const int E = in_sizes[1] / 2;
    const int* src = ei;
    const int* dst = ei + E;

    float* ws = (float*)d_ws;
    const int nb = (n + SCAN_B - 1) / SCAN_B;

    size_t u_dinv = 0;
    size_t u_offs = u_dinv + n;
    size_t u_cur  = u_offs + n + 16;
    size_t u_bsum = u_cur + n;
    size_t u_bq   = u_bsum + 1024;
    size_t u_h1   = u_bq + 2 * (size_t)E;
    size_t u_r1   = u_h1 + 16 * (size_t)n;
    size_t need   = (u_r1 + 16 * (size_t)n) * 4;

    if (ws_size >= need) {
        float* dinv = ws + u_dinv;
        int* offs   = (int*)(ws + u_offs);
        int* cursor = (int*)(ws + u_cur);
        int* bsum   = (int*)(ws + u_bsum);
        int2* bq    = (int2*)(ws + u_bq);
        float* h1   = ws + u_h1;
        float* r1   = ws + u_r1;
        int* cnt    = (int*)h1;      // alias (dead before gemm1 writes h1)
        float* agg2r = h1;           // alias (h1 dead after first k_agg)

        k_zero_i<<<(n + 255) / 256, 256, 0, stream>>>(cnt, n);
        k_count <<<(E + 255) / 256, 256, 0, stream>>>(dst, cnt, E);
        k_scan1 <<<nb, SCAN_B, 0, stream>>>(cnt, offs, bsum, n);
        k_scan2 <<<1, SCAN_B, 0, stream>>>(bsum, nb);
        k_scan3 <<<(n + 255) / 256, 256, 0, stream>>>(offs, bsum, cursor, cnt, dinv, n, E);
        k_gemm1 <<<1024, 256, 0, stream>>>(x, W1, dinv, h1, nullptr, n);
        k_fill  <<<(E + 255) / 256, 256, 0, stream>>>(src, dst, dinv, cursor, bq, E);
        k_agg   <<<(n * 16 + 255) / 256, 256, 0, stream>>>(h1, bq, offs, dinv, b1, r1, n, 1);
        k_agg   <<<(n * 16 + 255) / 256, 256, 0, stream>>>(r1, bq, offs, dinv, b1, agg2r, n, 0);
        k_out   <<<(n * 32 + 255) / 256, 256, 0, stream>>>(agg2r, W2, b2, out, n);
    } else {
        float* dinv = ws;
        float* h1   = ws + n;
        float* r1   = ws + n + 16 * (size_t)n;
        int* cnt    = (int*)h1;
        float* agg2r = h1;

        const int total1 = E * 16;
        k_zero_i   <<<(n + 255) / 256, 256, 0, stream>>>(cnt, n);
        k_count    <<<(E + 255) / 256, 256, 0, stream>>>(dst, cnt, E);
        k_dinv     <<<(n + 255) / 256, 256, 0, stream>>>(cnt, dinv, n);
        k_gemm1    <<<1024, 256, 0, stream>>>(x, W1, dinv, h1, r1, n);
        k_scatter16<<<(total1 + 255) / 256, 256, 0, stream>>>(src, dst, h1, dinv, r1, total1);
        k_relu16   <<<(n * 16 + 255) / 256, 256, 0, stream>>>(r1, b1, n * 16);
        k_self16   <<<(n * 16 + 255) / 256, 256, 0, stream>>>(r1, dinv, agg2r, n * 16);
        k_scatter16<<<(total1 + 255) / 256, 256, 0, stream>>>(src, dst, r1, dinv, agg2r, total1);
        k_out      <<<(n * 32 + 255) / 256, 256, 0, stream>>>(agg2r, W2, b2, out, n);
    }
}